// Round 1
// baseline (96.282 us; speedup 1.0000x reference)
//
#include <hip/hip_runtime.h>
#include <math.h>

// LSSL kernel: K[d,l] = Re sum_n (C*b_bar)[d,n] * a_bar[d,n]^l,  plus D passthrough.
// Bilinear discretization done per-(d,n) once per block into LDS; power sum via
// closed form r^l * (cos(l*theta), sin(l*theta)) using HW transcendentals.

#define STATE_DIM 64
#define BLOCK 256

__global__ __launch_bounds__(BLOCK) void lssl_kernel(
    const float* __restrict__ Lre, const float* __restrict__ Lim,
    const float* __restrict__ Bre, const float* __restrict__ Bim,
    const float* __restrict__ Cre, const float* __restrict__ Cim,
    const float* __restrict__ Dv,  const float* __restrict__ log_dt,
    float* __restrict__ out, int d_model, int L)
{
    const int d   = blockIdx.x;
    const int tid = threadIdx.x;

    __shared__ float s_log2r[STATE_DIM];
    __shared__ float s_threv[STATE_DIM];   // theta / (2*pi), for v_sin/v_cos (revolutions)
    __shared__ float s_wre[STATE_DIM];
    __shared__ float s_wim[STATE_DIM];

    if (tid < STATE_DIM) {
        const int n   = tid;
        const int idx = d * STATE_DIM + n;
        // lam = -softplus(Lre) + i*Lim   (softplus = max(x,0) + log1p(exp(-|x|)))
        float x      = Lre[idx];
        float sp     = fmaxf(x, 0.0f) + log1pf(expf(-fabsf(x)));
        float lam_re = -sp;
        float lam_im = Lim[idx];
        float dt     = expf(log_dt[d]);
        float hre    = 0.5f * dt * lam_re;
        float him    = 0.5f * dt * lam_im;
        // denom = 1 - h
        float dre = 1.0f - hre, dim = -him;
        float inv = 1.0f / (dre * dre + dim * dim);
        // a = (1 + h) / denom
        float nre = 1.0f + hre, nim = him;
        float are = (nre * dre + nim * dim) * inv;
        float aim = (nim * dre - nre * dim) * inv;
        // 1/denom = conj(denom) * inv
        float idre = dre * inv, idim = -dim * inv;
        // b_bar = dt/denom * B
        float bre = Bre[idx], bim = Bim[idx];
        float bbre = dt * (idre * bre - idim * bim);
        float bbim = dt * (idre * bim + idim * bre);
        // w = C * b_bar
        float cre = Cre[idx], cim = Cim[idx];
        float wre = cre * bbre - cim * bbim;
        float wim = cre * bbim + cim * bbre;

        float r2 = are * are + aim * aim;
        s_log2r[n] = 0.5f * log2f(r2);
        s_threv[n] = atan2f(aim, are) * 0.15915494309189535f; // theta / (2*pi)
        s_wre[n]   = wre;
        s_wim[n]   = wim;
    }
    __syncthreads();

    const int l = blockIdx.y * BLOCK + tid;
    if (l < L) {
        const float fl = (float)l;
        float acc = 0.0f;
        #pragma unroll
        for (int n = 0; n < STATE_DIM; ++n) {
            float e = __builtin_amdgcn_exp2f(fl * s_log2r[n]);   // r^l
            float t = fl * s_threv[n];
            t = t - floorf(t);                                   // fract -> [0,1) revolutions
            float s = __builtin_amdgcn_sinf(t);                  // sin(2*pi*t)
            float c = __builtin_amdgcn_cosf(t);                  // cos(2*pi*t)
            acc += e * (s_wre[n] * c - s_wim[n] * s);
        }
        out[(size_t)d * L + l] = acc;
    }
    if (blockIdx.y == 0 && tid == 0) {
        out[(size_t)d_model * L + d] = Dv[d];  // D output (tuple element 1)
    }
}

extern "C" void kernel_launch(void* const* d_in, const int* in_sizes, int n_in,
                              void* d_out, int out_size, void* d_ws, size_t ws_size,
                              hipStream_t stream) {
    const float* Lre    = (const float*)d_in[0];
    const float* Lim    = (const float*)d_in[1];
    const float* Bre    = (const float*)d_in[2];
    const float* Bim    = (const float*)d_in[3];
    const float* Cre    = (const float*)d_in[4];
    const float* Cim    = (const float*)d_in[5];
    const float* Dv     = (const float*)d_in[6];
    const float* log_dt = (const float*)d_in[7];
    float* out = (float*)d_out;

    const int d_model = in_sizes[6];               // 512
    const int L       = out_size / d_model - 1;    // K is d_model*L, D is d_model

    dim3 grid(d_model, (L + BLOCK - 1) / BLOCK);
    lssl_kernel<<<grid, BLOCK, 0, stream>>>(Lre, Lim, Bre, Bim, Cre, Cim, Dv, log_dt,
                                            out, d_model, L);
}

// Round 2
// 82.985 us; speedup vs baseline: 1.1602x; 1.1602x over previous
//
#include <hip/hip_runtime.h>
#include <math.h>

// LSSL kernel: K[d,l] = Re sum_n (C*b_bar)[d,n] * a_bar[d,n]^l,  plus D passthrough.
//
// R1 structure: one block per (d, l-chunk). Preamble (64 threads) does the bilinear
// discretization and stores per-n params in LDS:
//   s_wa[n] = {w_re, w_im, aS_re, aS_im}   (aS = a^BLOCK, the per-j step factor)
//   s_lt[n] = {log2|a|, arg(a)/2pi}
// Main loop: each thread owns LT columns l = l0 + tid + j*BLOCK. Per n it computes
// p = w * a^(l0+tid) via 3 transcendentals ONCE, then steps j with a 4-op complex
// multiply by a^BLOCK (+1 acc add). 8x fewer transcendentals/LDS reads than R0;
// ~5 VALU ops per output-element-contribution is the inner floor.

#define STATE_DIM 64
#define BLOCK 256
#define LT 8

__global__ __launch_bounds__(BLOCK) void lssl_kernel(
    const float* __restrict__ Lre, const float* __restrict__ Lim,
    const float* __restrict__ Bre, const float* __restrict__ Bim,
    const float* __restrict__ Cre, const float* __restrict__ Cim,
    const float* __restrict__ Dv,  const float* __restrict__ log_dt,
    float* __restrict__ out, int d_model, int L)
{
    const int d   = blockIdx.x;
    const int tid = threadIdx.x;

    __shared__ float4 s_wa[STATE_DIM];  // w_re, w_im, aS_re, aS_im
    __shared__ float2 s_lt[STATE_DIM];  // log2|a|, arg(a)/(2*pi)

    if (tid < STATE_DIM) {
        const int n   = tid;
        const int idx = d * STATE_DIM + n;
        // lam = -softplus(Lre) + i*Lim
        float x      = Lre[idx];
        float sp     = fmaxf(x, 0.0f) + log1pf(expf(-fabsf(x)));
        float lam_re = -sp;
        float lam_im = Lim[idx];
        float dt     = expf(log_dt[d]);
        float hre    = 0.5f * dt * lam_re;
        float him    = 0.5f * dt * lam_im;
        float dre = 1.0f - hre, dim = -him;
        float inv = 1.0f / (dre * dre + dim * dim);
        float nre = 1.0f + hre, nim = him;
        float are = (nre * dre + nim * dim) * inv;   // a_bar
        float aim = (nim * dre - nre * dim) * inv;
        float idre = dre * inv, idim = -dim * inv;   // 1/denom
        float bre = Bre[idx], bim = Bim[idx];
        float bbre = dt * (idre * bre - idim * bim); // b_bar
        float bbim = dt * (idre * bim + idim * bre);
        float cre = Cre[idx], cim = Cim[idx];
        float wre = cre * bbre - cim * bbim;         // w = C * b_bar
        float wim = cre * bbim + cim * bbre;

        float r2    = are * are + aim * aim;
        float log2r = 0.5f * log2f(r2);
        float threv = atan2f(aim, are) * 0.15915494309189535f;  // arg(a)/2pi

        // step factor a^BLOCK
        float eS = __builtin_amdgcn_exp2f((float)BLOCK * log2r);
        float tS = (float)BLOCK * threv;
        tS -= floorf(tS);
        float aSre = eS * __builtin_amdgcn_cosf(tS);
        float aSim = eS * __builtin_amdgcn_sinf(tS);

        s_wa[n] = make_float4(wre, wim, aSre, aSim);
        s_lt[n] = make_float2(log2r, threv);
    }
    __syncthreads();

    const int l0 = blockIdx.y * (BLOCK * LT);
    const float fl0 = (float)(l0 + tid);

    float acc[LT];
    #pragma unroll
    for (int j = 0; j < LT; ++j) acc[j] = 0.0f;

    #pragma unroll 4
    for (int n = 0; n < STATE_DIM; ++n) {
        float4 wa = s_wa[n];
        float2 lt = s_lt[n];
        // u = a^(l0+tid)
        float e = __builtin_amdgcn_exp2f(fl0 * lt.x);
        float t = fl0 * lt.y;
        t -= floorf(t);
        float s = __builtin_amdgcn_sinf(t);
        float c = __builtin_amdgcn_cosf(t);
        float ure = e * c, uim = e * s;
        // p = w * u
        float pre = wa.x * ure - wa.y * uim;
        float pim = wa.x * uim + wa.y * ure;
        acc[0] += pre;
        #pragma unroll
        for (int j = 1; j < LT; ++j) {
            // p *= a^BLOCK
            float t0  = pre * wa.z;
            float t1  = pre * wa.w;
            float nr  = fmaf(-pim, wa.w, t0);
            float ni  = fmaf( pim, wa.z, t1);
            pre = nr; pim = ni;
            acc[j] += pre;
        }
    }

    float* orow = out + (size_t)d * L;
    #pragma unroll
    for (int j = 0; j < LT; ++j) {
        int l = l0 + tid + j * BLOCK;
        if (l < L) orow[l] = acc[j];
    }
    if (tid == 0 && blockIdx.y == 0) {
        out[(size_t)d_model * L + d] = Dv[d];  // D output (tuple element 1)
    }
}

extern "C" void kernel_launch(void* const* d_in, const int* in_sizes, int n_in,
                              void* d_out, int out_size, void* d_ws, size_t ws_size,
                              hipStream_t stream) {
    const float* Lre    = (const float*)d_in[0];
    const float* Lim    = (const float*)d_in[1];
    const float* Bre    = (const float*)d_in[2];
    const float* Bim    = (const float*)d_in[3];
    const float* Cre    = (const float*)d_in[4];
    const float* Cim    = (const float*)d_in[5];
    const float* Dv     = (const float*)d_in[6];
    const float* log_dt = (const float*)d_in[7];
    float* out = (float*)d_out;

    const int d_model = in_sizes[6];               // 512
    const int L       = out_size / d_model - 1;    // K is d_model*L, D is d_model

    const int chunk = BLOCK * LT;                  // l-range covered per block
    dim3 grid(d_model, (L + chunk - 1) / chunk);
    lssl_kernel<<<grid, BLOCK, 0, stream>>>(Lre, Lim, Bre, Bim, Cre, Cim, Dv, log_dt,
                                            out, d_model, L);
}